// Round 1
// baseline (114.618 us; speedup 1.0000x reference)
//
#include <hip/hip_runtime.h>
#include <math.h>
#include <float.h>

// Problem constants (match reference)
#define BATCH 4
#define KCLS 16
#define NSRC 4096
#define NTGT 16384

// geometry: 512 threads = 8 waves; 8 targets/lane -> 512 targets/block;
// sources split 8-ways across blocks (grid = 4*32*8 = 1024 -> 4 blocks/CU).
#define THREADS 512
#define WAVES 8
#define TPL 8                               // targets per lane
#define TGT_PER_BLOCK 512                   // 64 lanes * TPL
#define SPLITS 8
#define CHUNK (NSRC / SPLITS)               // 512 sources per split-chunk
#define STRIPE (CHUNK / WAVES)              // 64 sources per wave

// workspace layout (assumes ws_size >= ~4.6 MB; prior sessions used d_ws freely)
//   [0,              256K)  float4 packed[B*NSRC]   (x,y,z,ss)
//   [256K,           320K)  float  maxlog[B*NSRC]   per-source max class logit
//   [320K,  320K+4M)        u64    part[B][SPLITS][NTGT] packed (ord<<32)|idx
#define WS_PACKED 0
#define WS_MAXLOG (BATCH * NSRC * 16)
#define WS_PART   (WS_MAXLOG + BATCH * NSRC * 4)

// ---------------------------------------------------------------------------
// pack_kernel: replaces the memset node. Builds the float4 source array with
// precomputed ss (EXACT same rounding chain as the verified staging code) and
// the per-source max-class logit (EXACT same ascending fmaxf chain the old
// gate used) so gate does 1 gather instead of 16.
// ---------------------------------------------------------------------------
__global__ __launch_bounds__(256) void pack_kernel(
    const float* __restrict__ source_pos,   // [B, 3, NS]
    const float* __restrict__ sem_logits,   // [B, K, NS]
    float4* __restrict__ packed,            // [B*NS]
    float* __restrict__ maxlog)             // [B*NS]
{
    int g = blockIdx.x * 256 + threadIdx.x;   // 0 .. B*NSRC-1
    int b = g >> 12;                          // NSRC == 4096
    int s = g & (NSRC - 1);

    const float* sxp = source_pos + (size_t)b * 3 * NSRC;
    float x = sxp[s], y = sxp[NSRC + s], z = sxp[2 * NSRC + s];
    float ss = __fadd_rn(__fadd_rn(__fmul_rn(x, x), __fmul_rn(y, y)),
                         __fmul_rn(z, z));
    packed[g] = make_float4(x, y, z, ss);

    const float* lg = sem_logits + (size_t)b * KCLS * NSRC + s;
    float mm = lg[0];
#pragma unroll
    for (int k = 1; k < KCLS; ++k) mm = fmaxf(mm, lg[(size_t)k * NSRC]);
    maxlog[g] = mm;
}

// ---------------------------------------------------------------------------
// nn_kernel: per-(target, source-chunk) argmin partials. Bit-exact numerics
// (same __fmul_rn/__fmaf_rn/__fadd_rn chain verified at absmax=0.0):
//   ss/tt: squares rounded individually, then sequential sum
//   dot  : rn(tx*sx); fma(ty,sy,.); fma(tz,sz,.)
//   d2   : fma(-2, dot, rn(tt+ss))
// Sources are read as WAVE-UNIFORM float4 loads (readfirstlane-forced SGPR
// base -> scalar s_load path; co-issues on the scalar pipe, no LDS staging,
// no ds_read in the hot loop, single __syncthreads for the wave-combine).
// Cross-split combine moved to gate via plain coalesced u64 stores (no
// atomics, no init/memset needed).
// ---------------------------------------------------------------------------
__global__ __launch_bounds__(THREADS) void nn_kernel(
    const float4* __restrict__ packed,      // [B*NS] (x,y,z,ss)
    const float* __restrict__ target_pos,   // [B, 3, NT]
    unsigned long long* __restrict__ part)  // [B][SPLITS][NTGT]
{
    __shared__ float smin[WAVES * TGT_PER_BLOCK];   // 16 KB
    __shared__ int   sidx[WAVES * TGT_PER_BLOCK];   // 16 KB

    int tid = threadIdx.x;
    int lane = tid & 63;
    int wave = tid >> 6;                    // 0..7

    // grid decode: blocksPerBatch = 32 tgroups * 8 splits = 256
    int b = blockIdx.x >> 8;
    int rem = blockIdx.x & 255;
    int tg = rem >> 3;
    int split = rem & 7;
    int tbase = tg * TGT_PER_BLOCK;
    int cg = split * CHUNK;                 // this block's source-chunk base

    // eight targets per lane: t_j = tbase + 64*j + lane (coalesced loads)
    const float* tp = target_pos + (size_t)b * 3 * NTGT;
    float tx[TPL], ty[TPL], tz[TPL], tt[TPL];
#pragma unroll
    for (int j = 0; j < TPL; ++j) {
        int t = tbase + 64 * j + lane;
        tx[j] = tp[t]; ty[j] = tp[NTGT + t]; tz[j] = tp[2 * NTGT + t];
        tt[j] = __fadd_rn(__fadd_rn(__fmul_rn(tx[j], tx[j]),
                                    __fmul_rn(ty[j], ty[j])),
                          __fmul_rn(tz[j], tz[j]));
    }

    // wave-uniform source pointer: force the stripe base into an SGPR so the
    // uniformity analysis can emit scalar loads for sp[i].
    int gbase = cg + wave * STRIPE;         // global source index base
    int ubase = __builtin_amdgcn_readfirstlane(gbase);
    const float4* sp = packed + (size_t)b * NSRC + ubase;

    float best[TPL];
    int bi[TPL];
#pragma unroll
    for (int j = 0; j < TPL; ++j) { best[j] = FLT_MAX; bi[j] = 0; }

    // depth-1 register prefetch of 4 sources/group; all indexing static.
    float4 cur[4], nxt[4];
#pragma unroll
    for (int k = 0; k < 4; ++k) cur[k] = sp[k];

    for (int i0 = 0; i0 < STRIPE; i0 += 4) {
        // final iteration over-reads 64 B past this stripe's rows — lands in
        // the maxlog region of ws (mapped, unused values): harmless.
#pragma unroll
        for (int k = 0; k < 4; ++k) nxt[k] = sp[i0 + 4 + k];
#pragma unroll
        for (int k = 0; k < 4; ++k) {
            float4 f = cur[k];
            int cand = gbase + i0 + k;
#pragma unroll
            for (int j = 0; j < TPL; ++j) {
                float acc = __fmul_rn(tx[j], f.x);
                acc = __fmaf_rn(ty[j], f.y, acc);
                acc = __fmaf_rn(tz[j], f.z, acc);
                float d2 = __fmaf_rn(-2.0f, acc, __fadd_rn(tt[j], f.w));
                if (d2 < best[j]) { best[j] = d2; bi[j] = cand; }  // strict '<'
            }
        }
#pragma unroll
        for (int k = 0; k < 4; ++k) cur[k] = nxt[k];
    }

    // cross-wave combine in LDS (waves cover ascending source stripes, so
    // ascending-w scan with strict-less + tie->lower-index == np.argmin).
#pragma unroll
    for (int j = 0; j < TPL; ++j) {
        smin[wave * TGT_PER_BLOCK + 64 * j + lane] = best[j];
        sidx[wave * TGT_PER_BLOCK + 64 * j + lane] = bi[j];
    }
    __syncthreads();

    {
        int t = tid;                        // TGT_PER_BLOCK == THREADS
        float m = smin[t];
        int mi = sidx[t];
#pragma unroll
        for (int w = 1; w < WAVES; ++w) {
            float mj = smin[w * TGT_PER_BLOCK + t];
            int ij = sidx[w * TGT_PER_BLOCK + t];
            if (mj < m || (mj == m && ij < mi)) { m = mj; mi = ij; }
        }
        // total-order map: monotone wrt float '<' (handles negatives); the
        // packed u64 compares lexicographically as (d2, first index).
        unsigned u = __float_as_uint(m);
        unsigned ord = (u & 0x80000000u) ? ~u : (u | 0x80000000u);
        part[((size_t)b * SPLITS + split) * NTGT + tbase + t] =
            ((unsigned long long)ord << 32) | (unsigned)mi;
    }
}

// ---------------------------------------------------------------------------
// gate_kernel: combine the 8 split-partials (plain u64 '<' min == the old
// atomicMin lexicographic semantics, bit-identical winner), then ONE gather
// from the 64 KB L2-hot maxlog table + sigmoid.
// ---------------------------------------------------------------------------
__global__ __launch_bounds__(256) void gate_kernel(
    const unsigned long long* __restrict__ part,  // [B][SPLITS][NTGT]
    const float* __restrict__ maxlog,             // [B*NS]
    float* __restrict__ out)                      // [B*NT]
{
    int gt = blockIdx.x * 256 + threadIdx.x;      // 0 .. B*NT-1
    int b = gt >> 14;                             // NTGT == 16384
    int t = gt & (NTGT - 1);

    const unsigned long long* pp = part + (size_t)b * SPLITS * NTGT + t;
    unsigned long long best = pp[0];
#pragma unroll
    for (int s = 1; s < SPLITS; ++s) {
        unsigned long long v = pp[(size_t)s * NTGT];  // coalesced in t
        if (v < best) best = v;
    }
    int mi = (int)(best & 0xFFFFFFFFull);

    float mm = maxlog[(b << 12) + mi];            // NSRC == 4096
    out[gt] = 1.0f / (1.0f + expf(-mm));
}

extern "C" void kernel_launch(void* const* d_in, const int* in_sizes, int n_in,
                              void* d_out, int out_size, void* d_ws, size_t ws_size,
                              hipStream_t stream) {
    const float* sem_logits = (const float*)d_in[0];   // [B,K,NS] fp32
    const float* source_pos = (const float*)d_in[1];   // [B,3,NS] fp32
    const float* target_pos = (const float*)d_in[2];   // [B,3,NT] fp32
    float* out = (float*)d_out;                        // [B,NT,1] fp32

    char* ws = (char*)d_ws;
    float4* packed = (float4*)(ws + WS_PACKED);
    float* maxlog = (float*)(ws + WS_MAXLOG);
    unsigned long long* part = (unsigned long long*)(ws + WS_PART);

    pack_kernel<<<(BATCH * NSRC) / 256, 256, 0, stream>>>(
        source_pos, sem_logits, packed, maxlog);
    nn_kernel<<<BATCH * (NTGT / TGT_PER_BLOCK) * SPLITS, THREADS, 0, stream>>>(
        packed, target_pos, part);
    gate_kernel<<<(BATCH * NTGT) / 256, 256, 0, stream>>>(part, maxlog, out);
}

// Round 2
// 100.478 us; speedup vs baseline: 1.1407x; 1.1407x over previous
//
#include <hip/hip_runtime.h>
#include <math.h>
#include <float.h>

// Problem constants (match reference)
#define BATCH 4
#define KCLS 16
#define NSRC 4096
#define NTGT 16384

// geometry: 512 threads = 8 waves; 8 targets/lane -> 512 targets/block;
// sources split 4-ways across blocks (grid = 4*32*4 = 512 -> 2 blocks/CU).
// Fewer splits than R0 (was 8): inner-loop work per wave doubles (~16K cyc)
// so the fixed prologue/epilogue (~2-3K cyc) amortizes twice as well.
#define THREADS 512
#define WAVES 8
#define TPL 8                               // targets per lane
#define TGT_PER_BLOCK 512                   // 64 lanes * TPL
#define SPLITS 4
#define CHUNK (NSRC / SPLITS)               // 1024 sources per block
#define STRIPE (CHUNK / WAVES)              // 128 iterations per wave

// workspace: u64 part[B][SPLITS][NTGT] packed (ord<<32)|idx  (2 MB)
// no init needed: every slot is written unconditionally each iteration.

// ---------------------------------------------------------------------------
// nn_kernel: per-(target, source-chunk) argmin partials, bit-exact numerics
// (verified absmax=0.0 chain):
//   ss/tt: squares rounded individually, then sequential sum
//   dot  : rn(tx*sx); fma(ty,sy,.); fma(tz,sz,.)
//   d2   : fma(-2, dot, rn(tt+ss))
// Sources staged in LDS (16 KB), consumed as wave-uniform ds_read_b128
// broadcasts (R0's proven hot loop). Epilogue: plain coalesced u64 store
// per (split, target) — no atomics, no memset node.
// ---------------------------------------------------------------------------
__global__ __launch_bounds__(THREADS) void nn_kernel(
    const float* __restrict__ source_pos,   // [B, 3, NS]
    const float* __restrict__ target_pos,   // [B, 3, NT]
    unsigned long long* __restrict__ part)  // [B][SPLITS][NTGT]
{
    // 32 KB: [0,16K) = float4 stage[1024]; aliased after the scan as
    // smin[8][512] (16 KB) | sidx[8][512] (16 KB) = 32 KB
    __shared__ float4 ls[CHUNK * 2];

    int tid = threadIdx.x;
    int lane = tid & 63;
    int wave = tid >> 6;                    // 0..7

    // grid decode: blocksPerBatch = 32 tgroups * 4 splits = 128
    int b = blockIdx.x >> 7;
    int rem = blockIdx.x & 127;
    int tg = rem >> 2;
    int split = rem & 3;
    int tbase = tg * TGT_PER_BLOCK;
    int cg = split * CHUNK;                 // this block's source-chunk base

    // stage chunk: 1024 sources, 2 per thread (coalesced x/y/z streams)
    const float* sxp = source_pos + (size_t)b * 3 * NSRC;
    const float* syp = sxp + NSRC;
    const float* szp = sxp + 2 * NSRC;
#pragma unroll
    for (int r = 0; r < CHUNK / THREADS; ++r) {
        int s = r * THREADS + tid;
        float x = sxp[cg + s], y = syp[cg + s], z = szp[cg + s];
        float ss = __fadd_rn(__fadd_rn(__fmul_rn(x, x), __fmul_rn(y, y)),
                             __fmul_rn(z, z));
        ls[s] = make_float4(x, y, z, ss);
    }

    // eight targets per lane: t_j = tbase + 64*j + lane (coalesced loads)
    const float* tp = target_pos + (size_t)b * 3 * NTGT;
    float tx[TPL], ty[TPL], tz[TPL], tt[TPL];
#pragma unroll
    for (int j = 0; j < TPL; ++j) {
        int t = tbase + 64 * j + lane;
        tx[j] = tp[t]; ty[j] = tp[NTGT + t]; tz[j] = tp[2 * NTGT + t];
        tt[j] = __fadd_rn(__fadd_rn(__fmul_rn(tx[j], tx[j]),
                                    __fmul_rn(ty[j], ty[j])),
                          __fmul_rn(tz[j], tz[j]));
    }

    __syncthreads();

    int lbase = wave * STRIPE;              // this wave's stripe in the chunk
    int gbase = cg + lbase;                 // global source index base (uniform)
    float best[TPL];
    int bi[TPL];
#pragma unroll
    for (int j = 0; j < TPL; ++j) { best[j] = FLT_MAX; bi[j] = 0; }

#pragma unroll 8
    for (int i = 0; i < STRIPE; ++i) {
        float4 f = ls[lbase + i];           // wave-uniform -> LDS broadcast
        int cand = gbase + i;
#pragma unroll
        for (int j = 0; j < TPL; ++j) {
            float acc = __fmul_rn(tx[j], f.x);
            acc = __fmaf_rn(ty[j], f.y, acc);
            acc = __fmaf_rn(tz[j], f.z, acc);
            float d2 = __fmaf_rn(-2.0f, acc, __fadd_rn(tt[j], f.w));
            if (d2 < best[j]) { best[j] = d2; bi[j] = cand; }  // strict '<'
        }
    }

    __syncthreads();                        // done READING ls before aliasing

    // cross-wave combine in LDS (waves cover ascending source stripes, so
    // ascending-w scan with strict-less + tie->lower-index == np.argmin).
    float* smin = (float*)ls;
    int* sidx = (int*)(smin + WAVES * TGT_PER_BLOCK);
#pragma unroll
    for (int j = 0; j < TPL; ++j) {
        smin[wave * TGT_PER_BLOCK + 64 * j + lane] = best[j];
        sidx[wave * TGT_PER_BLOCK + 64 * j + lane] = bi[j];
    }
    __syncthreads();

    {
        int t = tid;                        // TGT_PER_BLOCK == THREADS
        float m = smin[t];
        int mi = sidx[t];
#pragma unroll
        for (int w = 1; w < WAVES; ++w) {
            float mj = smin[w * TGT_PER_BLOCK + t];
            int ij = sidx[w * TGT_PER_BLOCK + t];
            if (mj < m || (mj == m && ij < mi)) { m = mj; mi = ij; }
        }
        // total-order map: monotone wrt float '<' (handles negatives); the
        // packed u64 compares lexicographically as (d2, first index).
        unsigned u = __float_as_uint(m);
        unsigned ord = (u & 0x80000000u) ? ~u : (u | 0x80000000u);
        part[((size_t)b * SPLITS + split) * NTGT + tbase + t] =
            ((unsigned long long)ord << 32) | (unsigned)mi;
    }
}

// ---------------------------------------------------------------------------
// gate_kernel: combine the 4 split-partials (plain u64 '<' min is exactly the
// old atomicMin lexicographic (d2, first-index) order — bit-identical winner),
// then the verified 16-way strided max over sem_logits (L2/L3-hot) + sigmoid.
// ---------------------------------------------------------------------------
__global__ __launch_bounds__(256) void gate_kernel(
    const unsigned long long* __restrict__ part,  // [B][SPLITS][NTGT]
    const float* __restrict__ sem_logits,         // [B, K, NS]
    float* __restrict__ out)                      // [B*NT]
{
    int gt = blockIdx.x * 256 + threadIdx.x;      // 0 .. B*NT-1
    int b = gt >> 14;                             // NTGT == 16384
    int t = gt & (NTGT - 1);

    const unsigned long long* pp = part + (size_t)b * SPLITS * NTGT + t;
    unsigned long long best = pp[0];
#pragma unroll
    for (int s = 1; s < SPLITS; ++s) {
        unsigned long long v = pp[(size_t)s * NTGT];  // coalesced in t
        if (v < best) best = v;
    }
    int mi = (int)(best & 0xFFFFFFFFull);

    const float* lg = sem_logits + (size_t)b * KCLS * NSRC + mi;
    float mm = lg[0];
#pragma unroll
    for (int k = 1; k < KCLS; ++k) mm = fmaxf(mm, lg[(size_t)k * NSRC]);
    out[gt] = 1.0f / (1.0f + expf(-mm));
}

extern "C" void kernel_launch(void* const* d_in, const int* in_sizes, int n_in,
                              void* d_out, int out_size, void* d_ws, size_t ws_size,
                              hipStream_t stream) {
    const float* sem_logits = (const float*)d_in[0];   // [B,K,NS] fp32
    const float* source_pos = (const float*)d_in[1];   // [B,3,NS] fp32
    const float* target_pos = (const float*)d_in[2];   // [B,3,NT] fp32
    float* out = (float*)d_out;                        // [B,NT,1] fp32

    unsigned long long* part = (unsigned long long*)d_ws;  // 2 MB partials

    nn_kernel<<<BATCH * (NTGT / TGT_PER_BLOCK) * SPLITS, THREADS, 0, stream>>>(
        source_pos, target_pos, part);
    gate_kernel<<<(BATCH * NTGT) / 256, 256, 0, stream>>>(part, sem_logits, out);
}